// Round 15
// baseline (232.052 us; speedup 1.0000x reference)
//
#include <hip/hip_runtime.h>
#include <hip/hip_bf16.h>

typedef short short8 __attribute__((ext_vector_type(8)));
typedef float floatx4 __attribute__((ext_vector_type(4)));

// hardware RTNE f32->bf16 (lowers to v_cvt_pk_bf16_f32 pairs; don't hand-roll — m240)
__device__ __forceinline__ unsigned short f2bf(float f) {
    __hip_bfloat16 h = __float2bfloat16(f);
    unsigned short u;
    __builtin_memcpy(&u, &h, 2);
    return u;
}

__device__ __forceinline__ float bf2f(unsigned short h) {
    union { unsigned int u; float f; } v;
    v.u = ((unsigned int)h) << 16;
    return v.f;
}

template <typename T>
__device__ __forceinline__ T ldany(const void* p) {
    T v;
    __builtin_memcpy(&v, p, sizeof(T));
    return v;
}

__device__ __forceinline__ void stany(void* p, floatx4 v) {
    __builtin_memcpy(p, &v, 16);
}

#define TPW 5  // tiles (of 16 rows) per wave
#define WPB 4  // waves per block (256 threads)

// out[n][d] = x[n][d] + sum_t mask(sigmoid(x[n]·tok[t])) * tok[t][d]
//
// Structure (round 13, 227.8us): ONE x layout serves GEMM1-B, GEMM2-C-init, store.
//  - xc[dt] = x[r0+ln][16dt+4q .. +3]  (8 dwordx4 per row)
//  - GEMM1 k-mapping permuted to match; tokA staged PRE-PERMUTED in LDS
//  - GEMM2 transposed: C/D = out[r0+ln][16dt+4q+p]; mfma accumulates INTO xc
//    (the +x is free via C-in); epilogue = 8 dwordx4 stores
// GEMM1 2-pass split precision: th·xh + th·xl (absmax 0.094 — rounds 8-14).
// W redistribution via __shfl (verified rounds 3-14).
// Prefetch + sched_barrier(0) (r7); NO asm keep-alive (r12: spills);
// no setprio (r14: null — no MFMA-pipe contention at 9% MfmaUtil).
// Round 15 geometry: 256-thread blocks (WPB=4). 512-thread blocks cap at
// 4 blocks/CU (32-wave limit) = 16 waves; 256-thread blocks fit 5 blocks/CU
// via LDS (5 x 32KB = 160KB) = 20 waves/CU (+25%), and grid 1563 -> 3125
// blocks halves the drain-tail imbalance (6.1 -> 12.2 blocks/CU).
// launch_bounds kept loose at (256,4): r11's spill came from its (256,5) cap.
__global__ __launch_bounds__(256, 4) void fused_prompt(
    const float* __restrict__ X, const float* __restrict__ Tok,
    float* __restrict__ Out, int N)
{
    // token LDS, XOR-swizzled: (row,col) at row*stride + (col ^ ((row&7)<<3))
    __shared__ unsigned short tokA[64 * 128];  // [t][k-pos] PERMUTED (GEMM1 A)
    __shared__ unsigned short tokT[128 * 64];  // [d][t]              (GEMM2 A)

    const int tid = threadIdx.x;

    // stage tokA: position (t, pos=32ks+8qp+j) holds Tok[t][32ks+16(j>>2)+4qp+(j&3)]
    for (int i = tid; i < 64 * 128; i += 256) {
        const int t = i >> 7, pos = i & 127;
        const int ks = pos >> 5, qp = (pos >> 3) & 3, j = pos & 7;
        const int d = (ks << 5) + ((j >> 2) << 4) + (qp << 2) + (j & 3);
        tokA[t * 128 + (pos ^ ((t & 7) << 3))] = f2bf(Tok[t * 128 + d]);
    }
    // stage tokT: [d][t] layout; i -> consecutive t => conflict-free writes
    for (int i = tid; i < 64 * 128; i += 256) {
        const int t = i & 63, d = i >> 6;
        tokT[d * 64 + (t ^ ((d & 7) << 3))] = f2bf(Tok[t * 128 + d]);
    }
    __syncthreads();

    const int lane = tid & 63;
    const int wave = tid >> 6;
    const int ln = lane & 15;  // fragment row/col index
    const int q = lane >> 4;   // k-group

    const long baseTile = ((long)blockIdx.x * WPB + wave) * TPW;
    if (baseTile * 16 >= N) return;  // tail wave: no work (barrier already passed)

    // prologue: issue tile-0 x loads (C2-layout: row r0+ln, d = 16dt+4q..+3)
    floatx4 xc[8];
    {
        const float* xr = X + (baseTile * 16 + ln) * 128 + q * 4;
#pragma unroll
        for (int dt = 0; dt < 8; ++dt) xc[dt] = ldany<floatx4>(xr + dt * 16);
    }

#pragma unroll
    for (int it = 0; it < TPW; ++it) {
        const long r0 = (baseTile + it) * 16;
        if (r0 >= N) return;  // tail guard

        // ---- prefetch next tile's x; sched_barrier pins the issue point ----
        floatx4 xn[8];
        if (it + 1 < TPW) {
            long pr = r0 + 16 + ln;
            if (pr >= N) pr = N - 1;  // clamp: last tiles must not read past X
            const float* xr = X + pr * 128 + q * 4;
#pragma unroll
            for (int dt = 0; dt < 8; ++dt) xn[dt] = ldany<floatx4>(xr + dt * 16);
        }
        __builtin_amdgcn_sched_barrier(0);  // prefetch loads may not sink below here

        // ---- convert x to bf16 hi/lo fragments under the permuted k-map ----
        // element j of k-group (ks): d = 32ks+16(j>>2)+4q+(j&3) = xc[2ks+(j>>2)][j&3]
        short8 xbh[4], xbl[4];
#pragma unroll
        for (int ks = 0; ks < 4; ++ks) {
#pragma unroll
            for (int j = 0; j < 8; ++j) {
                const float v = xc[2 * ks + (j >> 2)][j & 3];
                const unsigned short h = f2bf(v);
                xbh[ks][j] = (short)h;
                xbl[ks][j] = (short)f2bf(v - bf2f(h));
            }
        }

        // ======== GEMM1 (swapped): zT[64 x 16] = Tok[64x128] · Xtile^T ========
        floatx4 acc1[4];
#pragma unroll
        for (int tg = 0; tg < 4; ++tg) acc1[tg] = {0.f, 0.f, 0.f, 0.f};

#pragma unroll
        for (int ks = 0; ks < 4; ++ks) {
            const int p0 = ks * 32 + q * 8;  // position in permuted tokA row
#pragma unroll
            for (int tg = 0; tg < 4; ++tg) {
                const int t = tg * 16 + ln;  // t&7 == ln&7
                const short8 ah = ldany<short8>(&tokA[t * 128 + (p0 ^ ((ln & 7) << 3))]);
                acc1[tg] = __builtin_amdgcn_mfma_f32_16x16x32_bf16(ah, xbh[ks], acc1[tg], 0, 0, 0);
                acc1[tg] = __builtin_amdgcn_mfma_f32_16x16x32_bf16(ah, xbl[ks], acc1[tg], 0, 0, 0);
            }
        }

        // ---- sigmoid + threshold mask; pack to bf16 pairs (hw cvt) ----
        // C1-swapped layout: lane (ln,q) holds z[t = tg*16 + q*4 + p][n = r0 + ln]
        unsigned int S[4][2];
#pragma unroll
        for (int tg = 0; tg < 4; ++tg) {
            unsigned short b[4];
#pragma unroll
            for (int p = 0; p < 4; ++p) {
                const float z = acc1[tg][p];
                const float e = __builtin_amdgcn_exp2f(z * -1.442695040888963f);
                float w = __builtin_amdgcn_rcpf(1.0f + e);
                if (w < 0.2f) w = 0.0f;
                b[p] = f2bf(w);
            }
            S[tg][0] = (unsigned)b[0] | ((unsigned)b[1] << 16);
            S[tg][1] = (unsigned)b[2] | ((unsigned)b[3] << 16);
        }

        // ---- C1 -> A2 fragment shuffle via __shfl ----
        // target: a2[k2] elem j = W[n=ln][t = 32k2 + 8q + j]
        // source word for (k2,q,w): tg = 2k2+(q>>1), q_src = 2(q&1)+(w>>1), wi = w&1
        union {
            unsigned int u[4];
            short8 s;
        } a2[2];
#pragma unroll
        for (int k2 = 0; k2 < 2; ++k2) {
#pragma unroll
            for (int w = 0; w < 4; ++w) {
                const int srcLane = ln + 16 * (2 * (q & 1) + (w >> 1));
                const int lo = __shfl((int)S[2 * k2][w & 1], srcLane, 64);
                const int hi = __shfl((int)S[2 * k2 + 1][w & 1], srcLane, 64);
                a2[k2].u[w] = (unsigned int)((q < 2) ? lo : hi);
            }
        }

        // ======== GEMM2 (transposed), accumulating INTO xc ========
        // outT[128x16] = Tok^T · W^T + X^T: lane (ln,q) reg p = out[r0+ln][16dt+4q+p]
#pragma unroll
        for (int k2 = 0; k2 < 2; ++k2) {
            const int t0 = k2 * 32 + q * 8;
#pragma unroll
            for (int dt = 0; dt < 8; ++dt) {
                const int d = dt * 16 + ln;  // d&7 == ln&7
                const short8 aT = ldany<short8>(&tokT[d * 64 + (t0 ^ ((ln & 7) << 3))]);
                xc[dt] = __builtin_amdgcn_mfma_f32_16x16x32_bf16(aT, a2[k2].s, xc[dt], 0, 0, 0);
            }
        }

        // ---- store (epilogue is 8 dwordx4 stores; +x already folded in) ----
        float* orow = Out + (r0 + ln) * 128 + q * 4;
#pragma unroll
        for (int dt = 0; dt < 8; ++dt) stany(orow + dt * 16, xc[dt]);

        // ---- rotate prefetch buffer ----
        if (it + 1 < TPW) {
#pragma unroll
            for (int u = 0; u < 8; ++u) xc[u] = xn[u];
        }
    }
}

extern "C" void kernel_launch(void* const* d_in, const int* in_sizes, int n_in,
                              void* d_out, int out_size, void* d_ws, size_t ws_size,
                              hipStream_t stream) {
    const float* X = (const float*)d_in[0];
    const float* Tok = (const float*)d_in[1];
    float* Out = (float*)d_out;
    const int N = in_sizes[0] / 128;                           // 1,000,000
    const int tiles = (N + 15) / 16;                           // 62,500
    const int blocks = (tiles + WPB * TPW - 1) / (WPB * TPW);  // 3,125
    fused_prompt<<<blocks, 256, 0, stream>>>(X, Tok, Out, N);
}

// Round 16
// 217.974 us; speedup vs baseline: 1.0646x; 1.0646x over previous
//
#include <hip/hip_runtime.h>
#include <hip/hip_bf16.h>

typedef short short8 __attribute__((ext_vector_type(8)));
typedef float floatx4 __attribute__((ext_vector_type(4)));

// hardware RTNE f32->bf16 (lowers to v_cvt_pk_bf16_f32 pairs; don't hand-roll — m240)
__device__ __forceinline__ unsigned short f2bf(float f) {
    __hip_bfloat16 h = __float2bfloat16(f);
    unsigned short u;
    __builtin_memcpy(&u, &h, 2);
    return u;
}

__device__ __forceinline__ float bf2f(unsigned short h) {
    union { unsigned int u; float f; } v;
    v.u = ((unsigned int)h) << 16;
    return v.f;
}

template <typename T>
__device__ __forceinline__ T ldany(const void* p) {
    T v;
    __builtin_memcpy(&v, p, sizeof(T));
    return v;
}

__device__ __forceinline__ void stany(void* p, floatx4 v) {
    __builtin_memcpy(p, &v, 16);
}

#define WPB 8        // waves per block (512 threads)
#define NBLOCKS 512  // persistent grid: exactly 2 blocks/CU resident (16 waves, VGPR-band cap)
#define WTOT (NBLOCKS * WPB)  // 4096 waves; each grid-strides tiles by WTOT

// out[n][d] = x[n][d] + sum_t mask(sigmoid(x[n]·tok[t])) * tok[t][d]
//
// Structure (round 13, 227.8us): ONE x layout serves GEMM1-B, GEMM2-C-init, store.
//  - xc[dt] = x[r0+ln][16dt+4q .. +3]  (8 dwordx4 per row)
//  - GEMM1 k-mapping permuted to match; tokA staged PRE-PERMUTED in LDS
//  - GEMM2 transposed: C/D = out[r0+ln][16dt+4q+p]; mfma accumulates INTO xc
//    (the +x is free via C-in); epilogue = 8 dwordx4 stores
// GEMM1 2-pass split precision: th·xh + th·xl (absmax 0.094 — rounds 8-15).
// W redistribution via __shfl (verified rounds 3-15).
// Prefetch + sched_barrier(0) (r7); NO asm keep-alive (r12: spills);
// no setprio (r14: null); 512-thread blocks (r15: 256-thr regressed).
// Round 16: PERSISTENT grid — 512 blocks (= 2 resident/CU exactly), waves
// grid-stride tiles by 4096. Kills the 3-round block-drain tail (r13 grid was
// 1563 blocks = 3.05 rounds/CU; final partial round ran at half occupancy).
// Staging drops to 512 executions; co-resident waves sweep contiguous ~32MB
// X slabs per stride-round.
__global__ __launch_bounds__(512, 4) void fused_prompt(
    const float* __restrict__ X, const float* __restrict__ Tok,
    float* __restrict__ Out, int N)
{
    // token LDS, XOR-swizzled: (row,col) at row*stride + (col ^ ((row&7)<<3))
    __shared__ unsigned short tokA[64 * 128];  // [t][k-pos] PERMUTED (GEMM1 A)
    __shared__ unsigned short tokT[128 * 64];  // [d][t]              (GEMM2 A)

    const int tid = threadIdx.x;

    // stage tokA: position (t, pos=32ks+8qp+j) holds Tok[t][32ks+16(j>>2)+4qp+(j&3)]
    for (int i = tid; i < 64 * 128; i += 512) {
        const int t = i >> 7, pos = i & 127;
        const int ks = pos >> 5, qp = (pos >> 3) & 3, j = pos & 7;
        const int d = (ks << 5) + ((j >> 2) << 4) + (qp << 2) + (j & 3);
        tokA[t * 128 + (pos ^ ((t & 7) << 3))] = f2bf(Tok[t * 128 + d]);
    }
    // stage tokT: [d][t] layout; i -> consecutive t => conflict-free writes
    for (int i = tid; i < 64 * 128; i += 512) {
        const int t = i & 63, d = i >> 6;
        tokT[d * 64 + (t ^ ((d & 7) << 3))] = f2bf(Tok[t * 128 + d]);
    }
    __syncthreads();

    const int lane = tid & 63;
    const int wave = tid >> 6;
    const int ln = lane & 15;  // fragment row/col index
    const int q = lane >> 4;   // k-group

    const int nTiles = N >> 4;  // 62,500
    long tile = (long)blockIdx.x * WPB + wave;  // 0..4095
    if (tile >= nTiles) return;

    // prologue: issue first tile's x loads (C2-layout: row r0+ln, d = 16dt+4q..+3)
    floatx4 xc[8];
    {
        const float* xr = X + (tile * 16 + ln) * 128 + q * 4;
#pragma unroll
        for (int dt = 0; dt < 8; ++dt) xc[dt] = ldany<floatx4>(xr + dt * 16);
    }

    for (; tile < nTiles; tile += WTOT) {
        const long r0 = tile * 16;
        const bool hasNext = (tile + WTOT) < nTiles;

        // ---- prefetch next tile's x; sched_barrier pins the issue point ----
        floatx4 xn[8];
        if (hasNext) {
            const float* xr = X + ((tile + WTOT) * 16 + ln) * 128 + q * 4;
#pragma unroll
            for (int dt = 0; dt < 8; ++dt) xn[dt] = ldany<floatx4>(xr + dt * 16);
        }
        __builtin_amdgcn_sched_barrier(0);  // prefetch loads may not sink below here

        // ---- convert x to bf16 hi/lo fragments under the permuted k-map ----
        // element j of k-group (ks): d = 32ks+16(j>>2)+4q+(j&3) = xc[2ks+(j>>2)][j&3]
        short8 xbh[4], xbl[4];
#pragma unroll
        for (int ks = 0; ks < 4; ++ks) {
#pragma unroll
            for (int j = 0; j < 8; ++j) {
                const float v = xc[2 * ks + (j >> 2)][j & 3];
                const unsigned short h = f2bf(v);
                xbh[ks][j] = (short)h;
                xbl[ks][j] = (short)f2bf(v - bf2f(h));
            }
        }

        // ======== GEMM1 (swapped): zT[64 x 16] = Tok[64x128] · Xtile^T ========
        floatx4 acc1[4];
#pragma unroll
        for (int tg = 0; tg < 4; ++tg) acc1[tg] = {0.f, 0.f, 0.f, 0.f};

#pragma unroll
        for (int ks = 0; ks < 4; ++ks) {
            const int p0 = ks * 32 + q * 8;  // position in permuted tokA row
#pragma unroll
            for (int tg = 0; tg < 4; ++tg) {
                const int t = tg * 16 + ln;  // t&7 == ln&7
                const short8 ah = ldany<short8>(&tokA[t * 128 + (p0 ^ ((ln & 7) << 3))]);
                acc1[tg] = __builtin_amdgcn_mfma_f32_16x16x32_bf16(ah, xbh[ks], acc1[tg], 0, 0, 0);
                acc1[tg] = __builtin_amdgcn_mfma_f32_16x16x32_bf16(ah, xbl[ks], acc1[tg], 0, 0, 0);
            }
        }

        // ---- sigmoid + threshold mask; pack to bf16 pairs (hw cvt) ----
        // C1-swapped layout: lane (ln,q) holds z[t = tg*16 + q*4 + p][n = r0 + ln]
        unsigned int S[4][2];
#pragma unroll
        for (int tg = 0; tg < 4; ++tg) {
            unsigned short b[4];
#pragma unroll
            for (int p = 0; p < 4; ++p) {
                const float z = acc1[tg][p];
                const float e = __builtin_amdgcn_exp2f(z * -1.442695040888963f);
                float w = __builtin_amdgcn_rcpf(1.0f + e);
                if (w < 0.2f) w = 0.0f;
                b[p] = f2bf(w);
            }
            S[tg][0] = (unsigned)b[0] | ((unsigned)b[1] << 16);
            S[tg][1] = (unsigned)b[2] | ((unsigned)b[3] << 16);
        }

        // ---- C1 -> A2 fragment shuffle via __shfl ----
        // target: a2[k2] elem j = W[n=ln][t = 32k2 + 8q + j]
        // source word for (k2,q,w): tg = 2k2+(q>>1), q_src = 2(q&1)+(w>>1), wi = w&1
        union {
            unsigned int u[4];
            short8 s;
        } a2[2];
#pragma unroll
        for (int k2 = 0; k2 < 2; ++k2) {
#pragma unroll
            for (int w = 0; w < 4; ++w) {
                const int srcLane = ln + 16 * (2 * (q & 1) + (w >> 1));
                const int lo = __shfl((int)S[2 * k2][w & 1], srcLane, 64);
                const int hi = __shfl((int)S[2 * k2 + 1][w & 1], srcLane, 64);
                a2[k2].u[w] = (unsigned int)((q < 2) ? lo : hi);
            }
        }

        // ======== GEMM2 (transposed), accumulating INTO xc ========
        // outT[128x16] = Tok^T · W^T + X^T: lane (ln,q) reg p = out[r0+ln][16dt+4q+p]
#pragma unroll
        for (int k2 = 0; k2 < 2; ++k2) {
            const int t0 = k2 * 32 + q * 8;
#pragma unroll
            for (int dt = 0; dt < 8; ++dt) {
                const int d = dt * 16 + ln;  // d&7 == ln&7
                const short8 aT = ldany<short8>(&tokT[d * 64 + (t0 ^ ((ln & 7) << 3))]);
                xc[dt] = __builtin_amdgcn_mfma_f32_16x16x32_bf16(aT, a2[k2].s, xc[dt], 0, 0, 0);
            }
        }

        // ---- store (epilogue is 8 dwordx4 stores; +x already folded in) ----
        float* orow = Out + (r0 + ln) * 128 + q * 4;
#pragma unroll
        for (int dt = 0; dt < 8; ++dt) stany(orow + dt * 16, xc[dt]);

        // ---- rotate prefetch buffer (static indices — rule #20) ----
        if (hasNext) {
#pragma unroll
            for (int u = 0; u < 8; ++u) xc[u] = xn[u];
        }
    }
}

extern "C" void kernel_launch(void* const* d_in, const int* in_sizes, int n_in,
                              void* d_out, int out_size, void* d_ws, size_t ws_size,
                              hipStream_t stream) {
    const float* X = (const float*)d_in[0];
    const float* Tok = (const float*)d_in[1];
    float* Out = (float*)d_out;
    const int N = in_sizes[0] / 128;  // 1,000,000 (N % 16 == 0)
    fused_prompt<<<NBLOCKS, 512, 0, stream>>>(X, Tok, Out, N);
}